// Round 3
// baseline (5139.193 us; speedup 1.0000x reference)
//
#include <hip/hip_runtime.h>
#include <hip/hip_bf16.h>

#define NN 50000
#define EE 800000
#define GG 64
#define RR 3
#define METAD 38
#define EPSV 1e-5f

typedef __hip_bfloat16 bf16;

__device__ __forceinline__ float b2f(bf16 v){ return __bfloat162float(v); }

// ---------------- dtype detector: are float inputs fp32 (1) or bf16 (0)? ----------------
__global__ __launch_bounds__(256) void detect_kernel(const void* __restrict__ xraw,
                                                     int* __restrict__ flag){
  __shared__ int found;
  if (threadIdx.x == 0) found = 0;
  __syncthreads();
  const unsigned short* u = (const unsigned short*)xraw;
  for (int i = threadIdx.x; i < 65536; i += 256){
    int e = (u[i] >> 7) & 0xFF;          // bf16 exponent field
    if (e >= 0xF0) found = 1;            // |v| >= 2^113: impossible for N(0,1) bf16 data
  }
  __syncthreads();
  if (threadIdx.x == 0) *flag = found;
}

// ---------------- generic convert-to-fp32 (dtype decided by flag) ----------------
__global__ __launch_bounds__(256) void cvt_kernel(const void* __restrict__ src,
                                                  float* __restrict__ dst, int n,
                                                  const int* __restrict__ flag){
  int i = blockIdx.x*256 + threadIdx.x;
  if (i >= n) return;
  if (*flag) dst[i] = ((const float*)src)[i];
  else       dst[i] = b2f(((const bf16*)src)[i]);
}

// ---------------- edge counts ----------------
__global__ __launch_bounds__(256) void count_kernel(const int* __restrict__ ei,
                                                    const int* __restrict__ et,
                                                    float* __restrict__ cnt){
  int e = blockIdx.x*256 + threadIdx.x;
  if (e < EE){
    int d = ei[EE + e];
    int t = et[e];
    unsafeAtomicAdd(&cnt[t*NN + d], 1.0f);
  }
}

__global__ __launch_bounds__(256) void recip_kernel(float* __restrict__ cnt){
  int i = blockIdx.x*256 + threadIdx.x;
  if (i < RR*NN) cnt[i] = 1.0f / fmaxf(cnt[i], 1.0f);
}

// ------- scatter one relation's K-chunk: Y[d][c] += h[src][c0+c] * rcnt[r][d] -------
__global__ __launch_bounds__(256) void scatter_rel(const float* __restrict__ h, int ldh,
                                                   float* __restrict__ Y, int cwlog2, int c0, int r,
                                                   const int* __restrict__ ei,
                                                   const int* __restrict__ et,
                                                   const float* __restrict__ rcnt){
  long idx = (long)blockIdx.x*256 + threadIdx.x;
  if (idx >= ((long)EE << cwlog2)) return;
  int e = (int)(idx >> cwlog2);
  int c = ((int)idx) & ((1 << cwlog2) - 1);
  if (et[e] != r) return;
  int col = c0 + c;
  if (col >= ldh) return;
  int s = ei[e], d = ei[EE + e];
  float v = h[(size_t)s*ldh + col] * rcnt[r*NN + d];
  unsafeAtomicAdd(&Y[((size_t)d << cwlog2) + c], v);
}

// ------- GEMM pass: mode 0: C = A@W + bias ; mode 1: C += A@W (all fp32) -------
__global__ __launch_bounds__(256) void gemm_k(const float* __restrict__ A, int lda,
                                              int kw, int kwp,
                                              const float* __restrict__ Wm,
                                              const float* __restrict__ bias,
                                              float* __restrict__ C, int dout, int mode){
  __shared__ float As[16][68];
  __shared__ float Bs[16][68];
  int tid = threadIdx.x;
  int row0 = blockIdx.x*64, col0 = blockIdx.y*64;
  int tx = tid & 15, ty = tid >> 4;
  float acc[4][4] = {};
  for (int k0 = 0; k0 < kwp; k0 += 16){
    #pragma unroll
    for (int i = 0; i < 4; ++i){
      int idx = tid + i*256;
      int ak = idx & 15, am = idx >> 4;
      int gm = row0 + am, kl = k0 + ak;
      As[ak][am] = (gm < NN && kl < kw) ? A[(size_t)gm*lda + kl] : 0.f;
    }
    #pragma unroll
    for (int i = 0; i < 4; ++i){
      int idx = tid + i*256;
      int bn = idx & 63, bk = idx >> 6;
      int kl = k0 + bk, gc = col0 + bn;
      Bs[bk][bn] = (gc < dout && kl < kw) ? Wm[(size_t)kl*dout + gc] : 0.f;
    }
    __syncthreads();
    #pragma unroll
    for (int kk = 0; kk < 16; ++kk){
      const float4 a4 = *(const float4*)&As[kk][ty*4];
      const float4 b4 = *(const float4*)&Bs[kk][tx*4];
      const float av[4] = {a4.x, a4.y, a4.z, a4.w};
      const float bv[4] = {b4.x, b4.y, b4.z, b4.w};
      #pragma unroll
      for (int j = 0; j < 4; ++j)
        #pragma unroll
        for (int i = 0; i < 4; ++i)
          acc[j][i] = fmaf(av[j], bv[i], acc[j][i]);
    }
    __syncthreads();
  }
  #pragma unroll
  for (int j = 0; j < 4; ++j){
    int gm = row0 + ty*4 + j;
    int gc = col0 + tx*4;
    if (gm < NN && gc < dout){
      float4* p = (float4*)&C[(size_t)gm*dout + gc];
      float4 o;
      if (mode == 0){
        o.x = acc[j][0] + bias[gc+0];
        o.y = acc[j][1] + bias[gc+1];
        o.z = acc[j][2] + bias[gc+2];
        o.w = acc[j][3] + bias[gc+3];
      } else {
        float4 old = *p;
        o.x = old.x + acc[j][0];
        o.y = old.y + acc[j][1];
        o.z = old.z + acc[j][2];
        o.w = old.w + acc[j][3];
      }
      *p = o;
    }
  }
}

// ---------------- BN ----------------
__global__ __launch_bounds__(256) void bn_stats(const float* __restrict__ C, int dout,
                                                float* __restrict__ sums){
  int b = blockIdx.x;
  for (int c = threadIdx.x; c < dout; c += 256){
    float s = 0.f, q = 0.f;
    for (int n = b; n < NN; n += 256){
      float v = C[(size_t)n*dout + c];
      s += v; q += v*v;
    }
    unsafeAtomicAdd(&sums[c], s);
    unsafeAtomicAdd(&sums[256 + c], q);
  }
}

__global__ __launch_bounds__(256) void bn_finalize(const float* __restrict__ sums,
                                                   const float* __restrict__ g,
                                                   const float* __restrict__ bb,
                                                   float* __restrict__ scale,
                                                   float* __restrict__ shift, int dout){
  int c = threadIdx.x;
  if (c < dout){
    float mu = sums[c] * (1.0f/NN);
    float var = sums[256 + c] * (1.0f/NN) - mu*mu;
    float rstd = rsqrtf(fmaxf(var, 0.f) + EPSV);
    float s = rstd * g[c];
    scale[c] = s;
    shift[c] = bb[c] - mu*s;
  }
}

__global__ __launch_bounds__(256) void bn_apply(float* __restrict__ C,
                                                const float* __restrict__ scale,
                                                const float* __restrict__ shift, int dout){
  int n = blockIdx.x;
  for (int c = threadIdx.x; c < dout; c += 256)
    C[(size_t)n*dout + c] = C[(size_t)n*dout + c]*scale[c] + shift[c];
}

// ---------------- global mean pool (batch sorted) ----------------
__device__ __forceinline__ int lower_bound(const int* __restrict__ a, int v){
  int lo = 0, hi = NN;
  while (lo < hi){ int m = (lo+hi) >> 1; if (a[m] < v) lo = m+1; else hi = m; }
  return lo;
}

__global__ __launch_bounds__(256) void pool_kernel(const float* __restrict__ H,
                                                   const int* __restrict__ batch,
                                                   float* __restrict__ pooled){
  int g = blockIdx.x, sl = blockIdx.y;
  int start = lower_bound(batch, g), end = lower_bound(batch, g+1);
  int len = end - start;
  float inv = 1.0f / (float)max(len, 1);
  int chunk = (len + 7) >> 3;
  int s0 = start + sl*chunk;
  int s1 = min(s0 + chunk, end);
  float s = 0.f;
  for (int n = s0; n < s1; ++n) s += H[(size_t)n*256 + threadIdx.x];
  if (s1 > s0) unsafeAtomicAdd(&pooled[g*256 + threadIdx.x], s * inv);
}

// ---------------- final MLP (fp32 weights staged in ws; out dtype by flag) ----------------
__global__ __launch_bounds__(128) void final_kernel(const float* __restrict__ pooled,
                                                    const float* __restrict__ meta,
                                                    const float* __restrict__ w1,
                                                    const float* __restrict__ b1,
                                                    const float* __restrict__ w2,
                                                    const float* __restrict__ b2,
                                                    void* __restrict__ out,
                                                    const int* __restrict__ flag){
  int g = blockIdx.x;
  __shared__ float h1[100];
  __shared__ float red[128];
  int t = threadIdx.x;
  if (t < 100){
    float acc = b1[t];
    for (int k = 0; k < 256; ++k) acc += pooled[g*256 + k] * w1[k*100 + t];
    for (int k = 0; k < METAD; ++k) acc += meta[g*METAD + k] * w1[(256+k)*100 + t];
    h1[t] = acc;
  }
  __syncthreads();
  red[t] = (t < 100) ? h1[t] * w2[t] : 0.f;
  __syncthreads();
  for (int s = 64; s > 0; s >>= 1){
    if (t < s) red[t] += red[t + s];
    __syncthreads();
  }
  if (t == 0){
    float v = red[0] + b2[0];
    if (*flag) ((float*)out)[g] = v;
    else       ((bf16*)out)[g] = __float2bfloat16(v);
  }
}

// ---------------- launch ----------------
extern "C" void kernel_launch(void* const* d_in, const int* in_sizes, int n_in,
                              void* d_out, int out_size, void* d_ws, size_t ws_size,
                              hipStream_t stream){
  const void* x    = d_in[0];
  const int*  ei   = (const int*)d_in[2];
  const int*  et   = (const int*)d_in[3];
  const int*  batch= (const int*)d_in[5];

  // ---- workspace layout (fp32 elements), small/staged arrays first ----
  float* ws   = (float*)d_ws;
  int*   flag = (int*)ws;                          // [0..16)
  float* rcnt = ws + 16;                           // 150000
  float* sums = rcnt + 150000;                     // 512
  float* scale= sums + 512;                        // 256
  float* shift= scale + 256;                       // 256
  float* pooled = shift + 256;                     // 16384  -> ends 167424
  float* Wc   = pooled + 16384;                    // 508416 -> 675840
  float* Rc   = Wc + 508416;                       // 169472 -> 845312
  float* bc   = Rc + 169472;                       // 868
  float* gc_  = bc + 868;                          // 868
  float* bbc  = gc_ + 868;                         // 868
  float* metaf= bbc + 868;                         // 2432
  float* w1f  = metaf + 2432;                      // 29400
  float* b1f  = w1f + 29400;                       // 100
  float* w2f  = b1f + 100;                         // 100
  float* b2f_ = w2f + 100;                         // 1 (+pad)
  float* HA   = ws + 880000;                       // 12.8M
  float* HB   = HA + (size_t)NN*256;               // 12.8M -> ends 26,480,000 floats
  float* Y    = HB + (size_t)NN*256;

  // adaptive Y chunk width (pow2) based on actual ws_size
  long avail = (long)(ws_size / sizeof(float)) - 26480000L;
  int cwlog2 = 8;
  while (cwlog2 > 4 && ((long)NN << cwlog2) > avail) cwlog2--;

  // ---- dtype detect + stage all float inputs to fp32 ----
  detect_kernel<<<1, 256, 0, stream>>>(x, flag);
  auto cvt = [&](const void* src, float* dst, int n){
    cvt_kernel<<<(n + 255)/256, 256, 0, stream>>>(src, dst, n, flag);
  };
  const int Wsz[4]  = {38400, 76800, 196608, 196608};
  const int Woff[4] = {0, 38400, 115200, 311808};
  const int Rsz[4]  = {12800, 25600, 65536, 65536};
  const int Roff[4] = {0, 12800, 38400, 103936};
  const int vsz[4]  = {100, 256, 256, 256};
  const int voff[4] = {0, 100, 356, 612};
  float *Wf[4], *Rf[4], *bfp[4], *gf[4], *bbf[4];
  for (int l = 0; l < 4; ++l){
    Wf[l] = Wc + Woff[l];  Rf[l] = Rc + Roff[l];
    bfp[l] = bc + voff[l]; gf[l] = gc_ + voff[l];  bbf[l] = bbc + voff[l];
    cvt(d_in[6 + l*5 + 0], Wf[l],  Wsz[l]);
    cvt(d_in[6 + l*5 + 1], Rf[l],  Rsz[l]);
    cvt(d_in[6 + l*5 + 2], bfp[l], vsz[l]);
    cvt(d_in[6 + l*5 + 3], gf[l],  vsz[l]);
    cvt(d_in[6 + l*5 + 4], bbf[l], vsz[l]);
  }
  cvt(d_in[4],  metaf, GG*METAD);
  cvt(d_in[26], w1f, 29400);
  cvt(d_in[27], b1f, 100);
  cvt(d_in[28], w2f, 100);
  cvt(d_in[29], b2f_, 1);
  cvt(x, HA, NN*128);   // x -> fp32 H0

  hipMemsetAsync(rcnt, 0, 150000*sizeof(float), stream);
  count_kernel<<<(EE+255)/256, 256, 0, stream>>>(ei, et, rcnt);
  recip_kernel<<<(RR*NN+255)/256, 256, 0, stream>>>(rcnt);

  const int din[4] = {128, 100, 256, 256};
  const int dou[4] = {100, 256, 256, 256};
  float* hin = HA; float* hout = HB;
  for (int l = 0; l < 4; ++l){
    int D = din[l], O = dou[l];
    dim3 g2((NN+63)/64, (O+63)/64);

    int kwp = (D + 15) & ~15;
    gemm_k<<<g2, 256, 0, stream>>>(hin, D, D, kwp, Rf[l], bfp[l], hout, O, 0);

    int cl2 = cwlog2;
    while (cl2 > 4 && (1 << (cl2-1)) >= D) cl2--;
    int CW = 1 << cl2;

    for (int r = 0; r < RR; ++r){
      for (int c0 = 0; c0 < D; c0 += CW){
        int kw = (D - c0 < CW) ? (D - c0) : CW;
        int kwpc = (kw + 15) & ~15;
        hipMemsetAsync(Y, 0, ((size_t)NN << cl2)*sizeof(float), stream);
        long tot = (long)EE << cl2;
        int sblocks = (int)((tot + 255) / 256);
        scatter_rel<<<sblocks, 256, 0, stream>>>(hin, D, Y, cl2, c0, r, ei, et, rcnt);
        gemm_k<<<g2, 256, 0, stream>>>(Y, CW, kw, kwpc,
                                       Wf[l] + ((size_t)r*D + c0)*O, nullptr, hout, O, 1);
      }
    }

    hipMemsetAsync(sums, 0, 512*sizeof(float), stream);
    bn_stats<<<256, 256, 0, stream>>>(hout, O, sums);
    bn_finalize<<<1, 256, 0, stream>>>(sums, gf[l], bbf[l], scale, shift, O);
    bn_apply<<<NN, 256, 0, stream>>>(hout, scale, shift, O);

    float* tmp = hin; hin = hout; hout = tmp;
  }

  hipMemsetAsync(pooled, 0, (size_t)GG*256*sizeof(float), stream);
  pool_kernel<<<dim3(GG, 8), 256, 0, stream>>>(hin, batch, pooled);
  final_kernel<<<GG, 128, 0, stream>>>(pooled, metaf, w1f, b1f, w2f, b2f_, d_out, flag);
}

// Round 4
// 2858.595 us; speedup vs baseline: 1.7978x; 1.7978x over previous
//
#include <hip/hip_runtime.h>
#include <hip/hip_bf16.h>

#define NN 50000
#define EE 800000
#define GG 64
#define RR 3
#define METAD 38
#define NSEG (RR*NN)
#define EPSV 1e-5f

typedef __hip_bfloat16 bf16;

__device__ __forceinline__ float b2f(bf16 v){ return __bfloat162float(v); }

// ---------------- dtype detector: are float inputs fp32 (1) or bf16 (0)? ----------------
__global__ __launch_bounds__(256) void detect_kernel(const void* __restrict__ xraw,
                                                     int* __restrict__ flag){
  __shared__ int found;
  if (threadIdx.x == 0) found = 0;
  __syncthreads();
  const unsigned short* u = (const unsigned short*)xraw;
  for (int i = threadIdx.x; i < 65536; i += 256){
    int e = (u[i] >> 7) & 0xFF;
    if (e >= 0xF0) found = 1;
  }
  __syncthreads();
  if (threadIdx.x == 0) *flag = found;
}

__global__ __launch_bounds__(256) void cvt_kernel(const void* __restrict__ src,
                                                  float* __restrict__ dst, int n,
                                                  const int* __restrict__ flag){
  int i = blockIdx.x*256 + threadIdx.x;
  if (i >= n) return;
  if (*flag) dst[i] = ((const float*)src)[i];
  else       dst[i] = b2f(((const bf16*)src)[i]);
}

// ---------------- CSR build ----------------
__global__ __launch_bounds__(256) void counti_kernel(const int* __restrict__ ei,
                                                     const int* __restrict__ et,
                                                     int* __restrict__ cnt){
  int e = blockIdx.x*256 + threadIdx.x;
  if (e < EE) atomicAdd(&cnt[et[e]*NN + ei[EE + e]], 1);
}

__global__ __launch_bounds__(256) void rcnt_kernel(const int* __restrict__ cnt,
                                                   float* __restrict__ rcnt){
  int i = blockIdx.x*256 + threadIdx.x;
  if (i < NSEG) rcnt[i] = 1.0f / (float)max(cnt[i], 1);
}

__global__ __launch_bounds__(256) void scan1_kernel(const int* __restrict__ cnt,
                                                    int* __restrict__ segoff,
                                                    int* __restrict__ bsums){
  __shared__ int sh[256];
  int i = blockIdx.x*256 + threadIdx.x;
  int v = (i < NSEG) ? cnt[i] : 0;
  sh[threadIdx.x] = v;
  __syncthreads();
  for (int off = 1; off < 256; off <<= 1){
    int t = 0;
    if (threadIdx.x >= off) t = sh[threadIdx.x - off];
    __syncthreads();
    if (threadIdx.x >= off) sh[threadIdx.x] += t;
    __syncthreads();
  }
  if (i < NSEG) segoff[i] = sh[threadIdx.x] - v;   // block-local exclusive
  if (threadIdx.x == 255) bsums[blockIdx.x] = sh[255];
}

__global__ __launch_bounds__(256) void scan2_kernel(int* __restrict__ bsums, int nb){
  __shared__ int sh[256];
  __shared__ int carry;
  if (threadIdx.x == 0) carry = 0;
  __syncthreads();
  for (int base = 0; base < nb; base += 256){
    int i = base + threadIdx.x;
    int v = (i < nb) ? bsums[i] : 0;
    sh[threadIdx.x] = v;
    __syncthreads();
    for (int off = 1; off < 256; off <<= 1){
      int t = 0;
      if (threadIdx.x >= off) t = sh[threadIdx.x - off];
      __syncthreads();
      if (threadIdx.x >= off) sh[threadIdx.x] += t;
      __syncthreads();
    }
    if (i < nb) bsums[i] = sh[threadIdx.x] - v + carry;  // exclusive + carry
    __syncthreads();
    if (threadIdx.x == 0) carry += sh[255];
    __syncthreads();
  }
}

__global__ __launch_bounds__(256) void scan3_kernel(int* __restrict__ segoff,
                                                    const int* __restrict__ bsums){
  int i = blockIdx.x*256 + threadIdx.x;
  if (i < NSEG) segoff[i] += bsums[blockIdx.x];
  if (i == 0) segoff[NSEG] = EE;
}

__global__ __launch_bounds__(256) void curinit_kernel(const int* __restrict__ segoff,
                                                      int* __restrict__ cursor){
  int i = blockIdx.x*256 + threadIdx.x;
  if (i < NSEG) cursor[i] = segoff[i];
}

__global__ __launch_bounds__(256) void place_kernel(const int* __restrict__ ei,
                                                    const int* __restrict__ et,
                                                    int* __restrict__ cursor,
                                                    int* __restrict__ srcs){
  int e = blockIdx.x*256 + threadIdx.x;
  if (e < EE){
    int seg = et[e]*NN + ei[EE + e];
    int pos = atomicAdd(&cursor[seg], 1);
    srcs[pos] = ei[e];
  }
}

// ---------------- CSR gather aggregation: Y[d][c] = rcnt * sum_{e in seg(r,d)} h[src_e][c] ----------------
template<int D, int BS>
__global__ __launch_bounds__(BS) void aggregate_kernel(const float* __restrict__ h,
                                                       const int* __restrict__ segoff,
                                                       const int* __restrict__ srcs,
                                                       const float* __restrict__ rcnt,
                                                       float* __restrict__ Y, int r){
  int d = blockIdx.x;
  int t = threadIdx.x;
  int start = segoff[r*NN + d], end = segoff[r*NN + d + 1];
  float acc = 0.f;
  for (int e = start; e < end; ++e){
    int s = srcs[e];
    if (t < D) acc += h[(size_t)s*D + t];
  }
  if (t < D) Y[(size_t)d*D + t] = acc * rcnt[r*NN + d];
}

// ------- GEMM pass: mode 0: C = A@W + bias ; mode 1: C += A@W (all fp32) -------
__global__ __launch_bounds__(256) void gemm_k(const float* __restrict__ A, int lda,
                                              int kw, int kwp,
                                              const float* __restrict__ Wm,
                                              const float* __restrict__ bias,
                                              float* __restrict__ C, int dout, int mode){
  __shared__ float As[16][68];
  __shared__ float Bs[16][68];
  int tid = threadIdx.x;
  int row0 = blockIdx.x*64, col0 = blockIdx.y*64;
  int tx = tid & 15, ty = tid >> 4;
  float acc[4][4] = {};
  for (int k0 = 0; k0 < kwp; k0 += 16){
    #pragma unroll
    for (int i = 0; i < 4; ++i){
      int idx = tid + i*256;
      int ak = idx & 15, am = idx >> 4;
      int gm = row0 + am, kl = k0 + ak;
      As[ak][am] = (gm < NN && kl < kw) ? A[(size_t)gm*lda + kl] : 0.f;
    }
    #pragma unroll
    for (int i = 0; i < 4; ++i){
      int idx = tid + i*256;
      int bn = idx & 63, bk = idx >> 6;
      int kl = k0 + bk, gc = col0 + bn;
      Bs[bk][bn] = (gc < dout && kl < kw) ? Wm[(size_t)kl*dout + gc] : 0.f;
    }
    __syncthreads();
    #pragma unroll
    for (int kk = 0; kk < 16; ++kk){
      const float4 a4 = *(const float4*)&As[kk][ty*4];
      const float4 b4 = *(const float4*)&Bs[kk][tx*4];
      const float av[4] = {a4.x, a4.y, a4.z, a4.w};
      const float bv[4] = {b4.x, b4.y, b4.z, b4.w};
      #pragma unroll
      for (int j = 0; j < 4; ++j)
        #pragma unroll
        for (int i = 0; i < 4; ++i)
          acc[j][i] = fmaf(av[j], bv[i], acc[j][i]);
    }
    __syncthreads();
  }
  #pragma unroll
  for (int j = 0; j < 4; ++j){
    int gm = row0 + ty*4 + j;
    int gc = col0 + tx*4;
    if (gm < NN && gc < dout){
      float4* p = (float4*)&C[(size_t)gm*dout + gc];
      float4 o;
      if (mode == 0){
        o.x = acc[j][0] + bias[gc+0];
        o.y = acc[j][1] + bias[gc+1];
        o.z = acc[j][2] + bias[gc+2];
        o.w = acc[j][3] + bias[gc+3];
      } else {
        float4 old = *p;
        o.x = old.x + acc[j][0];
        o.y = old.y + acc[j][1];
        o.z = old.z + acc[j][2];
        o.w = old.w + acc[j][3];
      }
      *p = o;
    }
  }
}

// ---------------- BN ----------------
__global__ __launch_bounds__(256) void bn_stats(const float* __restrict__ C, int dout,
                                                float* __restrict__ sums){
  int b = blockIdx.x;
  for (int c = threadIdx.x; c < dout; c += 256){
    float s = 0.f, q = 0.f;
    for (int n = b; n < NN; n += 256){
      float v = C[(size_t)n*dout + c];
      s += v; q += v*v;
    }
    unsafeAtomicAdd(&sums[c], s);
    unsafeAtomicAdd(&sums[256 + c], q);
  }
}

__global__ __launch_bounds__(256) void bn_finalize(const float* __restrict__ sums,
                                                   const float* __restrict__ g,
                                                   const float* __restrict__ bb,
                                                   float* __restrict__ scale,
                                                   float* __restrict__ shift, int dout){
  int c = threadIdx.x;
  if (c < dout){
    float mu = sums[c] * (1.0f/NN);
    float var = sums[256 + c] * (1.0f/NN) - mu*mu;
    float rstd = rsqrtf(fmaxf(var, 0.f) + EPSV);
    float s = rstd * g[c];
    scale[c] = s;
    shift[c] = bb[c] - mu*s;
  }
}

__global__ __launch_bounds__(256) void bn_apply(float* __restrict__ C,
                                                const float* __restrict__ scale,
                                                const float* __restrict__ shift, int dout){
  int n = blockIdx.x;
  for (int c = threadIdx.x; c < dout; c += 256)
    C[(size_t)n*dout + c] = C[(size_t)n*dout + c]*scale[c] + shift[c];
}

// ---------------- global mean pool (batch sorted) ----------------
__device__ __forceinline__ int lower_bound(const int* __restrict__ a, int v){
  int lo = 0, hi = NN;
  while (lo < hi){ int m = (lo+hi) >> 1; if (a[m] < v) lo = m+1; else hi = m; }
  return lo;
}

__global__ __launch_bounds__(256) void pool_kernel(const float* __restrict__ H,
                                                   const int* __restrict__ batch,
                                                   float* __restrict__ pooled){
  int g = blockIdx.x, sl = blockIdx.y;
  int start = lower_bound(batch, g), end = lower_bound(batch, g+1);
  int len = end - start;
  float inv = 1.0f / (float)max(len, 1);
  int chunk = (len + 7) >> 3;
  int s0 = start + sl*chunk;
  int s1 = min(s0 + chunk, end);
  float s = 0.f;
  for (int n = s0; n < s1; ++n) s += H[(size_t)n*256 + threadIdx.x];
  if (s1 > s0) unsafeAtomicAdd(&pooled[g*256 + threadIdx.x], s * inv);
}

// ---------------- final MLP ----------------
__global__ __launch_bounds__(128) void final_kernel(const float* __restrict__ pooled,
                                                    const float* __restrict__ meta,
                                                    const float* __restrict__ w1,
                                                    const float* __restrict__ b1,
                                                    const float* __restrict__ w2,
                                                    const float* __restrict__ b2,
                                                    void* __restrict__ out,
                                                    const int* __restrict__ flag){
  int g = blockIdx.x;
  __shared__ float h1[100];
  __shared__ float red[128];
  int t = threadIdx.x;
  if (t < 100){
    float acc = b1[t];
    for (int k = 0; k < 256; ++k) acc += pooled[g*256 + k] * w1[k*100 + t];
    for (int k = 0; k < METAD; ++k) acc += meta[g*METAD + k] * w1[(256+k)*100 + t];
    h1[t] = acc;
  }
  __syncthreads();
  red[t] = (t < 100) ? h1[t] * w2[t] : 0.f;
  __syncthreads();
  for (int s = 64; s > 0; s >>= 1){
    if (t < s) red[t] += red[t + s];
    __syncthreads();
  }
  if (t == 0){
    float v = red[0] + b2[0];
    if (*flag) ((float*)out)[g] = v;
    else       ((bf16*)out)[g] = __float2bfloat16(v);
  }
}

// ---------------- launch ----------------
extern "C" void kernel_launch(void* const* d_in, const int* in_sizes, int n_in,
                              void* d_out, int out_size, void* d_ws, size_t ws_size,
                              hipStream_t stream){
  const void* x    = d_in[0];
  const int*  ei   = (const int*)d_in[2];
  const int*  et   = (const int*)d_in[3];
  const int*  batch= (const int*)d_in[5];

  // ---- workspace layout (4-byte elements) ----
  float* ws   = (float*)d_ws;
  int*   flag   = (int*)ws;                   // 16
  float* rcnt   = ws + 16;                    // 150000 -> 150016
  int*   cnt    = (int*)(ws + 150016);        // 150016 -> 300032
  int*   segoff = (int*)(ws + 300032);        // 150016 -> 450048
  int*   bsums  = (int*)(ws + 450048);        // 1024   -> 451072
  int*   srcs   = (int*)(ws + 451072);        // 800000 -> 1251072
  float* sums   = ws + 1251072;               // 512    -> 1251584
  float* scale  = ws + 1251584;               // 256
  float* shift  = ws + 1251840;               // 256
  float* pooled = ws + 1252096;               // 16384  -> 1268480
  float* Wc     = ws + 1268480;               // 508416 -> 1776896
  float* Rc     = ws + 1776896;               // 169472 -> 1946368
  float* bc     = ws + 1946368;               // 868
  float* gc_    = ws + 1947236;               // 868
  float* bbc    = ws + 1948104;               // 868
  float* metaf  = ws + 1948972;               // 2432
  float* w1f    = ws + 1951404;               // 29400
  float* b1f    = ws + 1980804;               // 100
  float* w2f    = ws + 1980904;               // 100
  float* b2f_   = ws + 1981004;               // 4 -> 1981008, pad
  float* HA     = ws + 1981056;               // 12.8M -> 14781056
  float* HB     = ws + 14781056;              // 12.8M -> 27581056
  float* Y      = ws + 27581056;              // 12.8M -> 40381056 (161.5 MB peak)
  int*   cursor = (int*)Y;                    // overlaid: used only before aggregation

  // ---- dtype detect + stage all float params to fp32 ----
  detect_kernel<<<1, 256, 0, stream>>>(x, flag);
  auto cvt = [&](const void* src, float* dst, int n){
    cvt_kernel<<<(n + 255)/256, 256, 0, stream>>>(src, dst, n, flag);
  };
  const int Wsz[4]  = {38400, 76800, 196608, 196608};
  const int Woff[4] = {0, 38400, 115200, 311808};
  const int Rsz[4]  = {12800, 25600, 65536, 65536};
  const int Roff[4] = {0, 12800, 38400, 103936};
  const int vsz[4]  = {100, 256, 256, 256};
  const int voff[4] = {0, 100, 356, 612};
  float *Wf[4], *Rf[4], *bfp[4], *gf[4], *bbf[4];
  for (int l = 0; l < 4; ++l){
    Wf[l] = Wc + Woff[l];  Rf[l] = Rc + Roff[l];
    bfp[l] = bc + voff[l]; gf[l] = gc_ + voff[l];  bbf[l] = bbc + voff[l];
    cvt(d_in[6 + l*5 + 0], Wf[l],  Wsz[l]);
    cvt(d_in[6 + l*5 + 1], Rf[l],  Rsz[l]);
    cvt(d_in[6 + l*5 + 2], bfp[l], vsz[l]);
    cvt(d_in[6 + l*5 + 3], gf[l],  vsz[l]);
    cvt(d_in[6 + l*5 + 4], bbf[l], vsz[l]);
  }
  cvt(d_in[4],  metaf, GG*METAD);
  cvt(d_in[26], w1f, 29400);
  cvt(d_in[27], b1f, 100);
  cvt(d_in[28], w2f, 100);
  cvt(d_in[29], b2f_, 1);
  cvt(x, HA, NN*128);

  // ---- CSR build (once; reused across all layers) ----
  hipMemsetAsync(cnt, 0, NSEG*sizeof(int), stream);
  counti_kernel<<<(EE+255)/256, 256, 0, stream>>>(ei, et, cnt);
  rcnt_kernel<<<(NSEG+255)/256, 256, 0, stream>>>(cnt, rcnt);
  int nb = (NSEG + 255)/256;   // 586
  scan1_kernel<<<nb, 256, 0, stream>>>(cnt, segoff, bsums);
  scan2_kernel<<<1, 256, 0, stream>>>(bsums, nb);
  scan3_kernel<<<nb, 256, 0, stream>>>(segoff, bsums);
  curinit_kernel<<<nb, 256, 0, stream>>>(segoff, cursor);
  place_kernel<<<(EE+255)/256, 256, 0, stream>>>(ei, et, cursor, srcs);

  const int din[4] = {128, 100, 256, 256};
  const int dou[4] = {100, 256, 256, 256};
  float* hin = HA; float* hout = HB;
  for (int l = 0; l < 4; ++l){
    int D = din[l], O = dou[l];
    dim3 g2((NN+63)/64, (O+63)/64);

    // root: C = hin @ Rw + bias
    int kwp = (D + 15) & ~15;
    gemm_k<<<g2, 256, 0, stream>>>(hin, D, D, kwp, Rf[l], bfp[l], hout, O, 0);

    for (int r = 0; r < RR; ++r){
      if (D == 256)      aggregate_kernel<256,256><<<NN, 256, 0, stream>>>(hin, segoff, srcs, rcnt, Y, r);
      else if (D == 128) aggregate_kernel<128,128><<<NN, 128, 0, stream>>>(hin, segoff, srcs, rcnt, Y, r);
      else               aggregate_kernel<100,128><<<NN, 128, 0, stream>>>(hin, segoff, srcs, rcnt, Y, r);
      gemm_k<<<g2, 256, 0, stream>>>(Y, D, D, kwp, Wf[l] + (size_t)r*D*O, nullptr, hout, O, 1);
    }

    hipMemsetAsync(sums, 0, 512*sizeof(float), stream);
    bn_stats<<<256, 256, 0, stream>>>(hout, O, sums);
    bn_finalize<<<1, 256, 0, stream>>>(sums, gf[l], bbf[l], scale, shift, O);
    bn_apply<<<NN, 256, 0, stream>>>(hout, scale, shift, O);

    float* tmp = hin; hin = hout; hout = tmp;
  }

  hipMemsetAsync(pooled, 0, (size_t)GG*256*sizeof(float), stream);
  pool_kernel<<<dim3(GG, 8), 256, 0, stream>>>(hin, batch, pooled);
  final_kernel<<<GG, 128, 0, stream>>>(pooled, metaf, w1f, b1f, w2f, b2f_, d_out, flag);
}

// Round 5
// 1759.404 us; speedup vs baseline: 2.9210x; 1.6248x over previous
//
#include <hip/hip_runtime.h>
#include <hip/hip_bf16.h>

#define NN 50000
#define EE 800000
#define GG 64
#define RR 3
#define METAD 38
#define NSEG (RR*NN)
#define EPSV 1e-5f

typedef __bf16 bf_t;
typedef __attribute__((ext_vector_type(8))) __bf16 bf16x8;
typedef __attribute__((ext_vector_type(4))) float f32x4;

__device__ __forceinline__ float loadf(const void* p, size_t i, int flag){
  return flag ? ((const float*)p)[i] : (float)(((const bf_t*)p)[i]);
}

// ---------------- dtype detector: fp32 (1) vs bf16 (0) ----------------
__global__ __launch_bounds__(256) void detect_kernel(const void* __restrict__ xraw,
                                                     int* __restrict__ flag){
  __shared__ int found;
  if (threadIdx.x == 0) found = 0;
  __syncthreads();
  const unsigned short* u = (const unsigned short*)xraw;
  for (int i = threadIdx.x; i < 65536; i += 256){
    int e = (u[i] >> 7) & 0xFF;
    if (e >= 0xF0) found = 1;
  }
  __syncthreads();
  if (threadIdx.x == 0) *flag = found;
}

__global__ __launch_bounds__(256) void cvt_kernel(const void* __restrict__ src,
                                                  float* __restrict__ dst, int n,
                                                  const int* __restrict__ flag){
  int i = blockIdx.x*256 + threadIdx.x;
  if (i < n) dst[i] = loadf(src, i, *flag);
}

// ---------------- pack weights: WbT[o][r*DP+i] = W[r][i][o] (bf16, zero-padded) ----------------
__global__ __launch_bounds__(256) void pack_w(const void* __restrict__ W,
                                              const void* __restrict__ R,
                                              bf_t* __restrict__ out,
                                              int D, int O, int dplog,
                                              const int* __restrict__ flag){
  int id = blockIdx.x*256 + threadIdx.x;
  int DP4 = 1 << (dplog + 2);
  int o = id >> (dplog + 2);
  int k = id & (DP4 - 1);
  int r = k >> dplog;
  int i = k & ((1 << dplog) - 1);
  float v = 0.f;
  int fl = *flag;
  if (i < D && o < O){
    if (r < 3) v = loadf(W, ((size_t)r*D + i)*O + o, fl);
    else       v = loadf(R, (size_t)i*O + o, fl);
  }
  out[(size_t)o*DP4 + k] = (bf_t)v;
}

// ---------------- CSR build ----------------
__global__ __launch_bounds__(256) void counti_kernel(const int* __restrict__ ei,
                                                     const int* __restrict__ et,
                                                     int* __restrict__ cnt){
  int e = blockIdx.x*256 + threadIdx.x;
  if (e < EE) atomicAdd(&cnt[et[e]*NN + ei[EE + e]], 1);
}

__global__ __launch_bounds__(256) void rcnt_kernel(const int* __restrict__ cnt,
                                                   float* __restrict__ rcnt){
  int i = blockIdx.x*256 + threadIdx.x;
  if (i < NSEG) rcnt[i] = 1.0f / (float)max(cnt[i], 1);
}

__global__ __launch_bounds__(256) void scan1_kernel(const int* __restrict__ cnt,
                                                    int* __restrict__ segoff,
                                                    int* __restrict__ bsums){
  __shared__ int sh[256];
  int i = blockIdx.x*256 + threadIdx.x;
  int v = (i < NSEG) ? cnt[i] : 0;
  sh[threadIdx.x] = v;
  __syncthreads();
  for (int off = 1; off < 256; off <<= 1){
    int t = 0;
    if (threadIdx.x >= off) t = sh[threadIdx.x - off];
    __syncthreads();
    if (threadIdx.x >= off) sh[threadIdx.x] += t;
    __syncthreads();
  }
  if (i < NSEG) segoff[i] = sh[threadIdx.x] - v;
  if (threadIdx.x == 255) bsums[blockIdx.x] = sh[255];
}

__global__ __launch_bounds__(256) void scan2_kernel(int* __restrict__ bsums, int nb){
  __shared__ int sh[256];
  __shared__ int carry;
  if (threadIdx.x == 0) carry = 0;
  __syncthreads();
  for (int base = 0; base < nb; base += 256){
    int i = base + threadIdx.x;
    int v = (i < nb) ? bsums[i] : 0;
    sh[threadIdx.x] = v;
    __syncthreads();
    for (int off = 1; off < 256; off <<= 1){
      int t = 0;
      if (threadIdx.x >= off) t = sh[threadIdx.x - off];
      __syncthreads();
      if (threadIdx.x >= off) sh[threadIdx.x] += t;
      __syncthreads();
    }
    if (i < nb) bsums[i] = sh[threadIdx.x] - v + carry;
    __syncthreads();
    if (threadIdx.x == 0) carry += sh[255];
    __syncthreads();
  }
}

__global__ __launch_bounds__(256) void scan3_kernel(int* __restrict__ segoff,
                                                    const int* __restrict__ bsums){
  int i = blockIdx.x*256 + threadIdx.x;
  if (i < NSEG) segoff[i] += bsums[blockIdx.x];
  if (i == 0) segoff[NSEG] = EE;
}

__global__ __launch_bounds__(256) void curinit_kernel(const int* __restrict__ segoff,
                                                      int* __restrict__ cursor){
  int i = blockIdx.x*256 + threadIdx.x;
  if (i < NSEG) cursor[i] = segoff[i];
}

__global__ __launch_bounds__(256) void place_kernel(const int* __restrict__ ei,
                                                    const int* __restrict__ et,
                                                    int* __restrict__ cursor,
                                                    int* __restrict__ srcs){
  int e = blockIdx.x*256 + threadIdx.x;
  if (e < EE){
    int seg = et[e]*NN + ei[EE + e];
    int pos = atomicAdd(&cursor[seg], 1);
    srcs[pos] = ei[e];
  }
}

// ---------------- x -> Ab slice3 (layer0, D=DP=128, lda=512) ----------------
__global__ __launch_bounds__(128) void cvt_x(const void* __restrict__ x,
                                             bf_t* __restrict__ Ab,
                                             const int* __restrict__ flag){
  int d = blockIdx.x, t = threadIdx.x;
  Ab[(size_t)d*512 + 384 + t] = (bf_t)loadf(x, (size_t)d*128 + t, *flag);
}

// ------- CSR gather mean into Ab slice r (bf16 in/out, pads propagate as 0) -------
template<int DP>
__global__ __launch_bounds__(DP) void aggregate_bf(const bf_t* __restrict__ Ab, int lda,
                                                   const int* __restrict__ segoff,
                                                   const int* __restrict__ srcs,
                                                   const float* __restrict__ rcnt,
                                                   bf_t* __restrict__ AbOut){
  int d = blockIdx.x, r = blockIdx.y, t = threadIdx.x;
  int seg = r*NN + d;
  int s0 = segoff[seg], s1 = segoff[seg+1];
  float acc = 0.f;
  const bf_t* in = Ab + 3*DP;   // slice 3 = bn(h)
  for (int e = s0; e < s1; ++e){
    int s = srcs[e];
    acc += (float)in[(size_t)s*lda + t];
  }
  AbOut[(size_t)d*lda + r*DP + t] = (bf_t)(acc * rcnt[seg]);
}

// ---------------- MFMA GEMM: C[NN][O] = Ab[NN][K] @ WbT^T + bias ----------------
// WbT is [Op][K] row-major (o-major), Op = gridDim.y*128. 128x128 tile, BK=64.
__global__ __launch_bounds__(256) void gemm_mfma(const bf_t* __restrict__ A, int lda, int K,
                                                 const bf_t* __restrict__ Bt,
                                                 const float* __restrict__ bias,
                                                 float* __restrict__ C, int O){
  __shared__ bf_t As[128][72];   // +8 pad: 144 B row stride, 16B-aligned chunks
  __shared__ bf_t Bs[128][72];
  int tid = threadIdx.x;
  int lane = tid & 63;
  int wave = tid >> 6;
  int row0 = blockIdx.x*128, col0 = blockIdx.y*128;
  int mw = (wave & 1) << 6, nw = (wave >> 1) << 6;
  int l15 = lane & 15, quad = lane >> 4;
  f32x4 acc[4][4] = {};
  uint4 av[4], bv[4];
  int sl8 = (tid & 7) * 8;
  int rbase = tid >> 3;

  // prefetch k0=0
  #pragma unroll
  for (int p = 0; p < 4; ++p){
    int row = p*32 + rbase;
    int gr = row0 + row; if (gr >= NN) gr = NN - 1;
    av[p] = *(const uint4*)(A + (size_t)gr*lda + sl8);
    bv[p] = *(const uint4*)(Bt + (size_t)(col0 + row)*K + sl8);
  }

  for (int k0 = 0; k0 < K; k0 += 64){
    __syncthreads();
    #pragma unroll
    for (int p = 0; p < 4; ++p){
      *(uint4*)&As[p*32 + rbase][sl8] = av[p];
      *(uint4*)&Bs[p*32 + rbase][sl8] = bv[p];
    }
    __syncthreads();
    if (k0 + 64 < K){
      int k1 = k0 + 64;
      #pragma unroll
      for (int p = 0; p < 4; ++p){
        int row = p*32 + rbase;
        int gr = row0 + row; if (gr >= NN) gr = NN - 1;
        av[p] = *(const uint4*)(A + (size_t)gr*lda + k1 + sl8);
        bv[p] = *(const uint4*)(Bt + (size_t)(col0 + row)*K + k1 + sl8);
      }
    }
    #pragma unroll
    for (int kk = 0; kk < 2; ++kk){
      bf16x8 af[4], bfv[4];
      int kc8 = (kk*4 + quad)*8;
      #pragma unroll
      for (int mi = 0; mi < 4; ++mi)
        af[mi] = *(const bf16x8*)&As[mw + mi*16 + l15][kc8];
      #pragma unroll
      for (int ni = 0; ni < 4; ++ni)
        bfv[ni] = *(const bf16x8*)&Bs[nw + ni*16 + l15][kc8];
      #pragma unroll
      for (int mi = 0; mi < 4; ++mi)
        #pragma unroll
        for (int ni = 0; ni < 4; ++ni)
          acc[mi][ni] = __builtin_amdgcn_mfma_f32_16x16x32_bf16(af[mi], bfv[ni], acc[mi][ni], 0, 0, 0);
    }
  }

  // epilogue: C/D layout col=lane&15, row=quad*4+reg  [guide §3, m89-verified]
  #pragma unroll
  for (int mi = 0; mi < 4; ++mi){
    int rb = row0 + mw + mi*16 + quad*4;
    #pragma unroll
    for (int ni = 0; ni < 4; ++ni){
      int col = col0 + nw + ni*16 + l15;
      if (col < O){
        float bz = bias[col];
        #pragma unroll
        for (int j = 0; j < 4; ++j){
          int rr = rb + j;
          if (rr < NN) C[(size_t)rr*O + col] = acc[mi][ni][j] + bz;
        }
      }
    }
  }
}

// ---------------- BN ----------------
__global__ __launch_bounds__(256) void bn_stats(const float* __restrict__ C, int dout,
                                                float* __restrict__ sums){
  int b = blockIdx.x;
  for (int c = threadIdx.x; c < dout; c += 256){
    float s = 0.f, q = 0.f;
    for (int n = b; n < NN; n += 256){
      float v = C[(size_t)n*dout + c];
      s += v; q += v*v;
    }
    unsafeAtomicAdd(&sums[c], s);
    unsafeAtomicAdd(&sums[256 + c], q);
  }
}

__global__ __launch_bounds__(256) void bn_finalize(const float* __restrict__ sums,
                                                   const float* __restrict__ g,
                                                   const float* __restrict__ bb,
                                                   float* __restrict__ scale,
                                                   float* __restrict__ shift, int dout){
  int c = threadIdx.x;
  if (c < dout){
    float mu = sums[c] * (1.0f/NN);
    float var = sums[256 + c] * (1.0f/NN) - mu*mu;
    float rstd = rsqrtf(fmaxf(var, 0.f) + EPSV);
    float s = rstd * g[c];
    scale[c] = s;
    shift[c] = bb[c] - mu*s;
  }
}

// BN apply fused with bf16 convert into Ab slice3 (next-layer layout)
template<int DPN>
__global__ __launch_bounds__(DPN) void bn_cvt(const float* __restrict__ C, int O,
                                              const float* __restrict__ scale,
                                              const float* __restrict__ shift,
                                              bf_t* __restrict__ Ab, int ldan){
  int d = blockIdx.x, t = threadIdx.x;
  float v = 0.f;
  if (t < O) v = C[(size_t)d*O + t]*scale[t] + shift[t];
  Ab[(size_t)d*ldan + 3*DPN + t] = (bf_t)v;
}

// ---------------- global mean pool (batch sorted, bf16 input from Ab slice3) ----------------
__device__ __forceinline__ int lower_bound(const int* __restrict__ a, int v){
  int lo = 0, hi = NN;
  while (lo < hi){ int m = (lo+hi) >> 1; if (a[m] < v) lo = m+1; else hi = m; }
  return lo;
}

__global__ __launch_bounds__(256) void pool_kernel(const bf_t* __restrict__ H, // = Ab + 768
                                                   const int* __restrict__ batch,
                                                   float* __restrict__ pooled){
  int g = blockIdx.x, sl = blockIdx.y;
  int start = lower_bound(batch, g), end = lower_bound(batch, g+1);
  int len = end - start;
  float inv = 1.0f / (float)max(len, 1);
  int chunk = (len + 7) >> 3;
  int s0 = start + sl*chunk;
  int s1 = min(s0 + chunk, end);
  float s = 0.f;
  for (int n = s0; n < s1; ++n) s += (float)H[(size_t)n*1024 + threadIdx.x];
  if (s1 > s0) unsafeAtomicAdd(&pooled[g*256 + threadIdx.x], s * inv);
}

// ---------------- final MLP ----------------
__global__ __launch_bounds__(128) void final_kernel(const float* __restrict__ pooled,
                                                    const float* __restrict__ meta,
                                                    const float* __restrict__ w1,
                                                    const float* __restrict__ b1,
                                                    const float* __restrict__ w2,
                                                    const float* __restrict__ b2,
                                                    void* __restrict__ out,
                                                    const int* __restrict__ flag){
  int g = blockIdx.x;
  __shared__ float h1[100];
  __shared__ float red[128];
  int t = threadIdx.x;
  if (t < 100){
    float acc = b1[t];
    for (int k = 0; k < 256; ++k) acc += pooled[g*256 + k] * w1[k*100 + t];
    for (int k = 0; k < METAD; ++k) acc += meta[g*METAD + k] * w1[(256+k)*100 + t];
    h1[t] = acc;
  }
  __syncthreads();
  red[t] = (t < 100) ? h1[t] * w2[t] : 0.f;
  __syncthreads();
  for (int s = 64; s > 0; s >>= 1){
    if (t < s) red[t] += red[t + s];
    __syncthreads();
  }
  if (t == 0){
    float v = red[0] + b2[0];
    if (*flag) ((float*)out)[g] = v;
    else       ((__hip_bfloat16*)out)[g] = __float2bfloat16(v);
  }
}

// ---------------- launch ----------------
extern "C" void kernel_launch(void* const* d_in, const int* in_sizes, int n_in,
                              void* d_out, int out_size, void* d_ws, size_t ws_size,
                              hipStream_t stream){
  const void* x    = d_in[0];
  const int*  ei   = (const int*)d_in[2];
  const int*  et   = (const int*)d_in[3];
  const int*  batch= (const int*)d_in[5];

  // ---- workspace layout (float units) ----
  float* ws     = (float*)d_ws;
  int*   flag   = (int*)ws;                    // 16
  float* rcnt   = ws + 16;                     // 150000 -> 150016
  int*   cnt    = (int*)(ws + 150016);         // -> 300016 (pad to 300032)
  int*   segoff = (int*)(ws + 300032);         // 150001 -> 450033 (pad 450048)
  int*   bsums  = (int*)(ws + 450048);         // 1024 -> 451072
  int*   srcs   = (int*)(ws + 451072);         // 800000 -> 1251072
  float* sums   = ws + 1251072;                // 512 -> 1251584
  float* scale  = ws + 1251584;                // 256
  float* shift  = ws + 1251840;                // 256
  float* pooled = ws + 1252096;                // 16384 -> 1268480
  float* bc     = ws + 1268480;                // 868
  float* gc_    = ws + 1269348;                // 868
  float* bbc    = ws + 1270216;                // 868
  float* metaf  = ws + 1271084;                // 2432
  float* w1f    = ws + 1273516;                // 29400
  float* b1f    = ws + 1302916;                // 100
  float* w2f    = ws + 1303016;                // 100
  float* b2f_   = ws + 1303116;                // 1 (pad to 1303168)
  bf_t*  wt     = (bf_t*)(ws + 1303168);       // 720896 shorts -> ends float 1663616
  int*   cursor = (int*)(ws + 1663616);        // 150000 -> 1813616 (pad 1813632)
  float* C      = ws + 1813632;                // 12800000 -> 14613632
  bf_t*  Ab     = (bf_t*)(ws + 14613632);      // 51200000 shorts -> ends 40213632 (160.9 MB)

  const size_t wtoff[4] = {0, 65536, 196608, 458752};

  // ---- dtype detect + stage small fp32 params ----
  detect_kernel<<<1, 256, 0, stream>>>(x, flag);
  auto cvt = [&](const void* src, float* dst, int n){
    cvt_kernel<<<(n + 255)/256, 256, 0, stream>>>(src, dst, n, flag);
  };
  const int vsz[4]  = {100, 256, 256, 256};
  const int voff[4] = {0, 100, 356, 612};
  float *bfp[4], *gf[4], *bbf[4];
  for (int l = 0; l < 4; ++l){
    bfp[l] = bc + voff[l]; gf[l] = gc_ + voff[l]; bbf[l] = bbc + voff[l];
    cvt(d_in[6 + l*5 + 2], bfp[l], vsz[l]);
    cvt(d_in[6 + l*5 + 3], gf[l],  vsz[l]);
    cvt(d_in[6 + l*5 + 4], bbf[l], vsz[l]);
  }
  cvt(d_in[4],  metaf, GG*METAD);
  cvt(d_in[26], w1f, 29400);
  cvt(d_in[27], b1f, 100);
  cvt(d_in[28], w2f, 100);
  cvt(d_in[29], b2f_, 1);

  // ---- pack weights to bf16 [Op][4*DP] ----
  const int din[4] = {128, 100, 256, 256};
  const int dou[4] = {100, 256, 256, 256};
  const int DP[4]  = {128, 128, 256, 256};
  const int dplog[4] = {7, 7, 8, 8};
  const int Op[4]  = {128, 256, 256, 256};
  for (int l = 0; l < 4; ++l){
    int total = Op[l] << (dplog[l] + 2);
    pack_w<<<total/256, 256, 0, stream>>>(d_in[6 + l*5 + 0], d_in[6 + l*5 + 1],
                                          wt + wtoff[l], din[l], dou[l], dplog[l], flag);
  }

  // ---- CSR build ----
  hipMemsetAsync(cnt, 0, NSEG*sizeof(int), stream);
  counti_kernel<<<(EE+255)/256, 256, 0, stream>>>(ei, et, cnt);
  rcnt_kernel<<<(NSEG+255)/256, 256, 0, stream>>>(cnt, rcnt);
  int nb = (NSEG + 255)/256;
  scan1_kernel<<<nb, 256, 0, stream>>>(cnt, segoff, bsums);
  scan2_kernel<<<1, 256, 0, stream>>>(bsums, nb);
  scan3_kernel<<<nb, 256, 0, stream>>>(segoff, bsums);
  curinit_kernel<<<nb, 256, 0, stream>>>(segoff, cursor);
  place_kernel<<<(EE+255)/256, 256, 0, stream>>>(ei, et, cursor, srcs);

  // ---- layer 0 input ----
  cvt_x<<<NN, 128, 0, stream>>>(x, Ab, flag);

  const int lda[4] = {512, 512, 1024, 1024};
  for (int l = 0; l < 4; ++l){
    int O = dou[l];
    // aggregation into Ab slices 0..2
    if (DP[l] == 128)
      aggregate_bf<128><<<dim3(NN, RR), 128, 0, stream>>>(Ab, lda[l], segoff, srcs, rcnt, Ab);
    else
      aggregate_bf<256><<<dim3(NN, RR), 256, 0, stream>>>(Ab, lda[l], segoff, srcs, rcnt, Ab);

    // fused GEMM
    dim3 g2(391, Op[l]/128);
    gemm_mfma<<<g2, 256, 0, stream>>>(Ab, lda[l], 4*DP[l], wt + wtoff[l], bfp[l], C, O);

    // BN
    hipMemsetAsync(sums, 0, 512*sizeof(float), stream);
    bn_stats<<<256, 256, 0, stream>>>(C, O, sums);
    bn_finalize<<<1, 256, 0, stream>>>(sums, gf[l], bbf[l], scale, shift, O);

    // BN-apply + bf16 convert into next layer's slice3
    int DPN = (l < 3) ? DP[l+1] : 256;
    int ldan = (l < 3) ? lda[l+1] : 1024;
    if (DPN == 128)
      bn_cvt<128><<<NN, 128, 0, stream>>>(C, O, scale, shift, Ab, ldan);
    else
      bn_cvt<256><<<NN, 256, 0, stream>>>(C, O, scale, shift, Ab, ldan);
  }

  hipMemsetAsync(pooled, 0, (size_t)GG*256*sizeof(float), stream);
  pool_kernel<<<dim3(GG, 8), 256, 0, stream>>>(Ab + 768, batch, pooled);
  final_kernel<<<GG, 128, 0, stream>>>(pooled, metaf, w1f, b1f, w2f, b2f_, d_out, flag);
}

// Round 6
// 1211.645 us; speedup vs baseline: 4.2415x; 1.4521x over previous
//
#include <hip/hip_runtime.h>
#include <hip/hip_bf16.h>

#define NN 50000
#define EE 800000
#define GG 64
#define RR 3
#define METAD 38
#define NSEG (RR*NN)
#define EPSV 1e-5f

typedef __bf16 bf_t;
typedef __attribute__((ext_vector_type(8))) __bf16 bf16x8;
typedef __attribute__((ext_vector_type(4))) __bf16 bf16x4;
typedef __attribute__((ext_vector_type(2))) __bf16 bf16x2;
typedef __attribute__((ext_vector_type(4))) float f32x4;

__device__ __forceinline__ float loadf(const void* p, size_t i, int flag){
  return flag ? ((const float*)p)[i] : (float)(((const bf_t*)p)[i]);
}

// ---------------- dtype detector: fp32 (1) vs bf16 (0) ----------------
__global__ __launch_bounds__(256) void detect_kernel(const void* __restrict__ xraw,
                                                     int* __restrict__ flag){
  __shared__ int found;
  if (threadIdx.x == 0) found = 0;
  __syncthreads();
  const unsigned short* u = (const unsigned short*)xraw;
  for (int i = threadIdx.x; i < 65536; i += 256){
    int e = (u[i] >> 7) & 0xFF;
    if (e >= 0xF0) found = 1;
  }
  __syncthreads();
  if (threadIdx.x == 0) *flag = found;
}

// ---------------- merged small-param convert ----------------
struct CvtJobs {
  const void* src[17];
  float* dst[17];
  int n[17];
};

__global__ __launch_bounds__(256) void cvt_many(CvtJobs j, const int* __restrict__ flag){
  int job = blockIdx.y;
  int i = blockIdx.x*256 + threadIdx.x;
  if (i < j.n[job]) j.dst[job][i] = loadf(j.src[job], i, *flag);
}

// ---------------- pack weights: WbT[o][r*DP+i] = W[r][i][o] (bf16, zero-padded) ----------------
__global__ __launch_bounds__(256) void pack_w(const void* __restrict__ W,
                                              const void* __restrict__ R,
                                              bf_t* __restrict__ out,
                                              int D, int O, int dplog,
                                              const int* __restrict__ flag){
  int id = blockIdx.x*256 + threadIdx.x;
  int DP4 = 1 << (dplog + 2);
  int o = id >> (dplog + 2);
  int k = id & (DP4 - 1);
  int r = k >> dplog;
  int i = k & ((1 << dplog) - 1);
  float v = 0.f;
  int fl = *flag;
  if (i < D && o < O){
    if (r < 3) v = loadf(W, ((size_t)r*D + i)*O + o, fl);
    else       v = loadf(R, (size_t)i*O + o, fl);
  }
  out[(size_t)o*DP4 + k] = (bf_t)v;
}

// ---------------- CSR build ----------------
__global__ __launch_bounds__(256) void counti_kernel(const int* __restrict__ ei,
                                                     const int* __restrict__ et,
                                                     int* __restrict__ cnt){
  int e = blockIdx.x*256 + threadIdx.x;
  if (e < EE) atomicAdd(&cnt[et[e]*NN + ei[EE + e]], 1);
}

__global__ __launch_bounds__(256) void rcnt_kernel(const int* __restrict__ cnt,
                                                   float* __restrict__ rcnt){
  int i = blockIdx.x*256 + threadIdx.x;
  if (i < NSEG) rcnt[i] = 1.0f / (float)max(cnt[i], 1);
}

__global__ __launch_bounds__(256) void scan1_kernel(const int* __restrict__ cnt,
                                                    int* __restrict__ segoff,
                                                    int* __restrict__ bsums){
  __shared__ int sh[256];
  int i = blockIdx.x*256 + threadIdx.x;
  int v = (i < NSEG) ? cnt[i] : 0;
  sh[threadIdx.x] = v;
  __syncthreads();
  for (int off = 1; off < 256; off <<= 1){
    int t = 0;
    if (threadIdx.x >= off) t = sh[threadIdx.x - off];
    __syncthreads();
    if (threadIdx.x >= off) sh[threadIdx.x] += t;
    __syncthreads();
  }
  if (i < NSEG) segoff[i] = sh[threadIdx.x] - v;
  if (threadIdx.x == 255) bsums[blockIdx.x] = sh[255];
}

__global__ __launch_bounds__(256) void scan2_kernel(int* __restrict__ bsums, int nb){
  __shared__ int sh[256];
  __shared__ int carry;
  if (threadIdx.x == 0) carry = 0;
  __syncthreads();
  for (int base = 0; base < nb; base += 256){
    int i = base + threadIdx.x;
    int v = (i < nb) ? bsums[i] : 0;
    sh[threadIdx.x] = v;
    __syncthreads();
    for (int off = 1; off < 256; off <<= 1){
      int t = 0;
      if (threadIdx.x >= off) t = sh[threadIdx.x - off];
      __syncthreads();
      if (threadIdx.x >= off) sh[threadIdx.x] += t;
      __syncthreads();
    }
    if (i < nb) bsums[i] = sh[threadIdx.x] - v + carry;
    __syncthreads();
    if (threadIdx.x == 0) carry += sh[255];
    __syncthreads();
  }
}

__global__ __launch_bounds__(256) void scan3_kernel(int* __restrict__ segoff,
                                                    const int* __restrict__ bsums){
  int i = blockIdx.x*256 + threadIdx.x;
  if (i < NSEG) segoff[i] += bsums[blockIdx.x];
  if (i == 0) segoff[NSEG] = EE;
}

__global__ __launch_bounds__(256) void curinit_kernel(const int* __restrict__ segoff,
                                                      int* __restrict__ cursor){
  int i = blockIdx.x*256 + threadIdx.x;
  if (i < NSEG) cursor[i] = segoff[i];
}

__global__ __launch_bounds__(256) void place_kernel(const int* __restrict__ ei,
                                                    const int* __restrict__ et,
                                                    int* __restrict__ cursor,
                                                    int* __restrict__ srcs){
  int e = blockIdx.x*256 + threadIdx.x;
  if (e < EE){
    int seg = et[e]*NN + ei[EE + e];
    int pos = atomicAdd(&cursor[seg], 1);
    srcs[pos] = ei[e];
  }
}

// ---------------- x -> Ab slice3 (layer0, D=DP=128, lda=512) ----------------
__global__ __launch_bounds__(128) void cvt_x(const void* __restrict__ x,
                                             bf_t* __restrict__ Ab,
                                             const int* __restrict__ flag){
  int d = blockIdx.x, t = threadIdx.x;
  Ab[(size_t)d*512 + 384 + t] = (bf_t)loadf(x, (size_t)d*128 + t, *flag);
}

// ------- wave-per-segment CSR gather mean: Y[d][r*DP+c] = rcnt * sum h[src][c] -------
// DP=256: lane covers 4 bf16 (uint2 load); DP=128: 2 bf16 (uint load). 4 waves/block.
template<int DP>
__global__ __launch_bounds__(256) void aggregate_wave(const bf_t* __restrict__ Ab, int lda,
                                                      const int* __restrict__ segoff,
                                                      const int* __restrict__ srcs,
                                                      const float* __restrict__ rcnt,
                                                      bf_t* __restrict__ out){
  int wid = (blockIdx.x*256 + threadIdx.x) >> 6;
  if (wid >= NSEG) return;
  int lane = threadIdx.x & 63;
  int r = wid / NN;                 // compile-time NN -> magic mul
  int d = wid - r*NN;
  int s0 = segoff[wid], s1 = segoff[wid + 1];
  const bf_t* in = Ab + 3*DP;       // slice 3 = bn(h)

  if (DP == 256){
    float a0=0.f, a1=0.f, a2=0.f, a3=0.f;
    const int off = lane*4;
    int e = s0;
    for (; e + 4 <= s1; e += 4){
      int sA = srcs[e], sB = srcs[e+1], sC = srcs[e+2], sD = srcs[e+3];
      uint2 vA = *(const uint2*)(in + (size_t)sA*lda + off);
      uint2 vB = *(const uint2*)(in + (size_t)sB*lda + off);
      uint2 vC = *(const uint2*)(in + (size_t)sC*lda + off);
      uint2 vD = *(const uint2*)(in + (size_t)sD*lda + off);
      a0 += __uint_as_float(vA.x << 16); a1 += __uint_as_float(vA.x & 0xFFFF0000u);
      a2 += __uint_as_float(vA.y << 16); a3 += __uint_as_float(vA.y & 0xFFFF0000u);
      a0 += __uint_as_float(vB.x << 16); a1 += __uint_as_float(vB.x & 0xFFFF0000u);
      a2 += __uint_as_float(vB.y << 16); a3 += __uint_as_float(vB.y & 0xFFFF0000u);
      a0 += __uint_as_float(vC.x << 16); a1 += __uint_as_float(vC.x & 0xFFFF0000u);
      a2 += __uint_as_float(vC.y << 16); a3 += __uint_as_float(vC.y & 0xFFFF0000u);
      a0 += __uint_as_float(vD.x << 16); a1 += __uint_as_float(vD.x & 0xFFFF0000u);
      a2 += __uint_as_float(vD.y << 16); a3 += __uint_as_float(vD.y & 0xFFFF0000u);
    }
    for (; e < s1; ++e){
      int s = srcs[e];
      uint2 v = *(const uint2*)(in + (size_t)s*lda + off);
      a0 += __uint_as_float(v.x << 16); a1 += __uint_as_float(v.x & 0xFFFF0000u);
      a2 += __uint_as_float(v.y << 16); a3 += __uint_as_float(v.y & 0xFFFF0000u);
    }
    float rc = rcnt[wid];
    bf16x4 o = {(bf_t)(a0*rc), (bf_t)(a1*rc), (bf_t)(a2*rc), (bf_t)(a3*rc)};
    *(bf16x4*)(out + (size_t)d*lda + r*DP + off) = o;
  } else {
    float a0=0.f, a1=0.f;
    const int off = lane*2;
    int e = s0;
    for (; e + 4 <= s1; e += 4){
      int sA = srcs[e], sB = srcs[e+1], sC = srcs[e+2], sD = srcs[e+3];
      unsigned vA = *(const unsigned*)(in + (size_t)sA*lda + off);
      unsigned vB = *(const unsigned*)(in + (size_t)sB*lda + off);
      unsigned vC = *(const unsigned*)(in + (size_t)sC*lda + off);
      unsigned vD = *(const unsigned*)(in + (size_t)sD*lda + off);
      a0 += __uint_as_float(vA << 16); a1 += __uint_as_float(vA & 0xFFFF0000u);
      a0 += __uint_as_float(vB << 16); a1 += __uint_as_float(vB & 0xFFFF0000u);
      a0 += __uint_as_float(vC << 16); a1 += __uint_as_float(vC & 0xFFFF0000u);
      a0 += __uint_as_float(vD << 16); a1 += __uint_as_float(vD & 0xFFFF0000u);
    }
    for (; e < s1; ++e){
      int s = srcs[e];
      unsigned v = *(const unsigned*)(in + (size_t)s*lda + off);
      a0 += __uint_as_float(v << 16); a1 += __uint_as_float(v & 0xFFFF0000u);
    }
    float rc = rcnt[wid];
    bf16x2 o = {(bf_t)(a0*rc), (bf_t)(a1*rc)};
    *(bf16x2*)(out + (size_t)d*lda + r*DP + off) = o;
  }
}

// ---------------- MFMA GEMM + fused BN-stats epilogue ----------------
// C[NN][O] = Ab[NN][K] @ WbT^T + bias; also sums[col] += col-sum, sums[256+col] += col-sumsq
__global__ __launch_bounds__(256) void gemm_mfma(const bf_t* __restrict__ A, int lda, int K,
                                                 const bf_t* __restrict__ Bt,
                                                 const float* __restrict__ bias,
                                                 float* __restrict__ C, int O,
                                                 float* __restrict__ sums){
  __shared__ bf_t As[128][72];
  __shared__ bf_t Bs[128][72];
  int tid = threadIdx.x;
  int lane = tid & 63;
  int wave = tid >> 6;
  int row0 = blockIdx.x*128, col0 = blockIdx.y*128;
  int mw = (wave & 1) << 6, nw = (wave >> 1) << 6;
  int l15 = lane & 15, quad = lane >> 4;
  f32x4 acc[4][4] = {};
  uint4 av[4], bv[4];
  int sl8 = (tid & 7) * 8;
  int rbase = tid >> 3;

  #pragma unroll
  for (int p = 0; p < 4; ++p){
    int row = p*32 + rbase;
    int gr = row0 + row; if (gr >= NN) gr = NN - 1;
    av[p] = *(const uint4*)(A + (size_t)gr*lda + sl8);
    bv[p] = *(const uint4*)(Bt + (size_t)(col0 + row)*K + sl8);
  }

  for (int k0 = 0; k0 < K; k0 += 64){
    __syncthreads();
    #pragma unroll
    for (int p = 0; p < 4; ++p){
      *(uint4*)&As[p*32 + rbase][sl8] = av[p];
      *(uint4*)&Bs[p*32 + rbase][sl8] = bv[p];
    }
    __syncthreads();
    if (k0 + 64 < K){
      int k1 = k0 + 64;
      #pragma unroll
      for (int p = 0; p < 4; ++p){
        int row = p*32 + rbase;
        int gr = row0 + row; if (gr >= NN) gr = NN - 1;
        av[p] = *(const uint4*)(A + (size_t)gr*lda + k1 + sl8);
        bv[p] = *(const uint4*)(Bt + (size_t)(col0 + row)*K + k1 + sl8);
      }
    }
    #pragma unroll
    for (int kk = 0; kk < 2; ++kk){
      bf16x8 af[4], bfv[4];
      int kc8 = (kk*4 + quad)*8;
      #pragma unroll
      for (int mi = 0; mi < 4; ++mi)
        af[mi] = *(const bf16x8*)&As[mw + mi*16 + l15][kc8];
      #pragma unroll
      for (int ni = 0; ni < 4; ++ni)
        bfv[ni] = *(const bf16x8*)&Bs[nw + ni*16 + l15][kc8];
      #pragma unroll
      for (int mi = 0; mi < 4; ++mi)
        #pragma unroll
        for (int ni = 0; ni < 4; ++ni)
          acc[mi][ni] = __builtin_amdgcn_mfma_f32_16x16x32_bf16(af[mi], bfv[ni], acc[mi][ni], 0, 0, 0);
    }
  }

  // epilogue: store C + per-column BN partials (C/D layout: col=lane&15, row=quad*4+reg)
  __syncthreads();                       // all waves done reading As/Bs
  float* colsum = (float*)As;            // reuse LDS: [0..128) sum, [128..256) sumsq
  if (tid < 256) colsum[tid] = 0.f;
  __syncthreads();
  #pragma unroll
  for (int ni = 0; ni < 4; ++ni){
    int lcol = nw + ni*16 + l15;
    int col = col0 + lcol;
    if (col < O){
      float bz = bias[col];
      float scol = 0.f, qcol = 0.f;
      #pragma unroll
      for (int mi = 0; mi < 4; ++mi){
        int rb = row0 + mw + mi*16 + quad*4;
        #pragma unroll
        for (int j = 0; j < 4; ++j){
          int rr = rb + j;
          if (rr < NN){
            float v = acc[mi][ni][j] + bz;
            C[(size_t)rr*O + col] = v;
            scol += v; qcol += v*v;
          }
        }
      }
      atomicAdd(&colsum[lcol], scol);
      atomicAdd(&colsum[128 + lcol], qcol);
    }
  }
  __syncthreads();
  if (tid < 128){
    int col = col0 + tid;
    if (col < O){
      unsafeAtomicAdd(&sums[col], colsum[tid]);
      unsafeAtomicAdd(&sums[256 + col], colsum[128 + tid]);
    }
  }
}

// ---------------- BN finalize ----------------
__global__ __launch_bounds__(256) void bn_finalize(const float* __restrict__ sums,
                                                   const float* __restrict__ g,
                                                   const float* __restrict__ bb,
                                                   float* __restrict__ scale,
                                                   float* __restrict__ shift, int dout){
  int c = threadIdx.x;
  if (c < dout){
    float mu = sums[c] * (1.0f/NN);
    float var = sums[256 + c] * (1.0f/NN) - mu*mu;
    float rstd = rsqrtf(fmaxf(var, 0.f) + EPSV);
    float s = rstd * g[c];
    scale[c] = s;
    shift[c] = bb[c] - mu*s;
  }
}

// BN apply fused with bf16 convert into Ab slice3 (next-layer layout)
template<int DPN>
__global__ __launch_bounds__(DPN) void bn_cvt(const float* __restrict__ C, int O,
                                              const float* __restrict__ scale,
                                              const float* __restrict__ shift,
                                              bf_t* __restrict__ Ab, int ldan){
  int d = blockIdx.x, t = threadIdx.x;
  float v = 0.f;
  if (t < O) v = C[(size_t)d*O + t]*scale[t] + shift[t];
  Ab[(size_t)d*ldan + 3*DPN + t] = (bf_t)v;
}

// ---------------- global mean pool (batch sorted, bf16 input from Ab slice3) ----------------
__device__ __forceinline__ int lower_bound(const int* __restrict__ a, int v){
  int lo = 0, hi = NN;
  while (lo < hi){ int m = (lo+hi) >> 1; if (a[m] < v) lo = m+1; else hi = m; }
  return lo;
}

__global__ __launch_bounds__(256) void pool_kernel(const bf_t* __restrict__ H,
                                                   const int* __restrict__ batch,
                                                   float* __restrict__ pooled){
  int g = blockIdx.x, sl = blockIdx.y;
  int start = lower_bound(batch, g), end = lower_bound(batch, g+1);
  int len = end - start;
  float inv = 1.0f / (float)max(len, 1);
  int chunk = (len + 7) >> 3;
  int s0 = start + sl*chunk;
  int s1 = min(s0 + chunk, end);
  float s = 0.f;
  for (int n = s0; n < s1; ++n) s += (float)H[(size_t)n*1024 + threadIdx.x];
  if (s1 > s0) unsafeAtomicAdd(&pooled[g*256 + threadIdx.x], s * inv);
}

// ---------------- final MLP ----------------
__global__ __launch_bounds__(128) void final_kernel(const float* __restrict__ pooled,
                                                    const float* __restrict__ meta,
                                                    const float* __restrict__ w1,
                                                    const float* __restrict__ b1,
                                                    const float* __restrict__ w2,
                                                    const float* __restrict__ b2,
                                                    void* __restrict__ out,
                                                    const int* __restrict__ flag){
  int g = blockIdx.x;
  __shared__ float h1[100];
  __shared__ float red[128];
  int t = threadIdx.x;
  if (t < 100){
    float acc = b1[t];
    for (int k = 0; k < 256; ++k) acc += pooled[g*256 + k] * w1[k*100 + t];
    for (int k = 0; k < METAD; ++k) acc += meta[g*METAD + k] * w1[(256+k)*100 + t];
    h1[t] = acc;
  }
  __syncthreads();
  red[t] = (t < 100) ? h1[t] * w2[t] : 0.f;
  __syncthreads();
  for (int s = 64; s > 0; s >>= 1){
    if (t < s) red[t] += red[t + s];
    __syncthreads();
  }
  if (t == 0){
    float v = red[0] + b2[0];
    if (*flag) ((float*)out)[g] = v;
    else       ((__hip_bfloat16*)out)[g] = __float2bfloat16(v);
  }
}

// ---------------- launch ----------------
extern "C" void kernel_launch(void* const* d_in, const int* in_sizes, int n_in,
                              void* d_out, int out_size, void* d_ws, size_t ws_size,
                              hipStream_t stream){
  const void* x    = d_in[0];
  const int*  ei   = (const int*)d_in[2];
  const int*  et   = (const int*)d_in[3];
  const int*  batch= (const int*)d_in[5];

  // ---- workspace layout (float units) ----
  float* ws     = (float*)d_ws;
  int*   flag   = (int*)ws;                    // 16
  float* rcnt   = ws + 16;                     // 150000 -> 150016
  int*   cnt    = (int*)(ws + 150016);         // -> 300016 (pad 300032)
  int*   segoff = (int*)(ws + 300032);         // 150001 -> (pad 450048)
  int*   bsums  = (int*)(ws + 450048);         // 1024 -> 451072
  int*   srcs   = (int*)(ws + 451072);         // 800000 -> 1251072
  float* sums   = ws + 1251072;                // 512 -> 1251584
  float* scale  = ws + 1251584;                // 256
  float* shift  = ws + 1251840;                // 256
  float* pooled = ws + 1252096;                // 16384 -> 1268480
  float* bc     = ws + 1268480;                // 868
  float* gc_    = ws + 1269348;                // 868
  float* bbc    = ws + 1270216;                // 868
  float* metaf  = ws + 1271084;                // 2432
  float* w1f    = ws + 1273516;                // 29400
  float* b1f    = ws + 1302916;                // 100
  float* w2f    = ws + 1303016;                // 100
  float* b2f_   = ws + 1303116;                // 1 (pad 1303168)
  bf_t*  wt     = (bf_t*)(ws + 1303168);       // 720896 bf16 -> 1663616
  int*   cursor = (int*)(ws + 1663616);        // 150000 -> (pad 1813632)
  float* C      = ws + 1813632;                // 12800000 -> 14613632
  bf_t*  Ab     = (bf_t*)(ws + 14613632);      // 51200000 bf16 -> 40213632 (160.9 MB)

  const size_t wtoff[4] = {0, 65536, 196608, 458752};

  detect_kernel<<<1, 256, 0, stream>>>(x, flag);

  // ---- merged small-param convert (17 jobs, one launch) ----
  const int vsz[4]  = {100, 256, 256, 256};
  const int voff[4] = {0, 100, 356, 612};
  float *bfp[4], *gf[4], *bbf[4];
  CvtJobs J;
  int nj = 0;
  for (int l = 0; l < 4; ++l){
    bfp[l] = bc + voff[l]; gf[l] = gc_ + voff[l]; bbf[l] = bbc + voff[l];
    J.src[nj] = d_in[6 + l*5 + 2]; J.dst[nj] = bfp[l]; J.n[nj] = vsz[l]; nj++;
    J.src[nj] = d_in[6 + l*5 + 3]; J.dst[nj] = gf[l];  J.n[nj] = vsz[l]; nj++;
    J.src[nj] = d_in[6 + l*5 + 4]; J.dst[nj] = bbf[l]; J.n[nj] = vsz[l]; nj++;
  }
  J.src[nj] = d_in[4];  J.dst[nj] = metaf; J.n[nj] = GG*METAD; nj++;
  J.src[nj] = d_in[26]; J.dst[nj] = w1f;   J.n[nj] = 29400; nj++;
  J.src[nj] = d_in[27]; J.dst[nj] = b1f;   J.n[nj] = 100; nj++;
  J.src[nj] = d_in[28]; J.dst[nj] = w2f;   J.n[nj] = 100; nj++;
  J.src[nj] = d_in[29]; J.dst[nj] = b2f_;  J.n[nj] = 1; nj++;
  cvt_many<<<dim3(115, nj), 256, 0, stream>>>(J, flag);

  // ---- pack weights to bf16 [Op][4*DP] ----
  const int din[4] = {128, 100, 256, 256};
  const int dou[4] = {100, 256, 256, 256};
  const int DP[4]  = {128, 128, 256, 256};
  const int dplog[4] = {7, 7, 8, 8};
  const int Op[4]  = {128, 256, 256, 256};
  for (int l = 0; l < 4; ++l){
    int total = Op[l] << (dplog[l] + 2);
    pack_w<<<total/256, 256, 0, stream>>>(d_in[6 + l*5 + 0], d_in[6 + l*5 + 1],
                                          wt + wtoff[l], din[l], dou[l], dplog[l], flag);
  }

  // ---- CSR build ----
  hipMemsetAsync(cnt, 0, NSEG*sizeof(int), stream);
  counti_kernel<<<(EE+255)/256, 256, 0, stream>>>(ei, et, cnt);
  rcnt_kernel<<<(NSEG+255)/256, 256, 0, stream>>>(cnt, rcnt);
  int nb = (NSEG + 255)/256;
  scan1_kernel<<<nb, 256, 0, stream>>>(cnt, segoff, bsums);
  scan2_kernel<<<1, 256, 0, stream>>>(bsums, nb);
  scan3_kernel<<<nb, 256, 0, stream>>>(segoff, bsums);
  curinit_kernel<<<nb, 256, 0, stream>>>(segoff, cursor);
  place_kernel<<<(EE+255)/256, 256, 0, stream>>>(ei, et, cursor, srcs);

  // ---- layer 0 input ----
  cvt_x<<<NN, 128, 0, stream>>>(x, Ab, flag);

  const int lda[4] = {512, 512, 1024, 1024};
  int aggBlocks = (NSEG + 3)/4;   // 4 waves per 256-block
  for (int l = 0; l < 4; ++l){
    int O = dou[l];
    if (DP[l] == 128)
      aggregate_wave<128><<<aggBlocks, 256, 0, stream>>>(Ab, lda[l], segoff, srcs, rcnt, Ab);
    else
      aggregate_wave<256><<<aggBlocks, 256, 0, stream>>>(Ab, lda[l], segoff, srcs, rcnt, Ab);

    hipMemsetAsync(sums, 0, 512*sizeof(float), stream);
    dim3 g2(391, Op[l]/128);
    gemm_mfma<<<g2, 256, 0, stream>>>(Ab, lda[l], 4*DP[l], wt + wtoff[l], bfp[l], C, O, sums);

    bn_finalize<<<1, 256, 0, stream>>>(sums, gf[l], bbf[l], scale, shift, O);

    int DPN = (l < 3) ? DP[l+1] : 256;
    int ldan = (l < 3) ? lda[l+1] : 1024;
    if (DPN == 128)
      bn_cvt<128><<<NN, 128, 0, stream>>>(C, O, scale, shift, Ab, ldan);
    else
      bn_cvt<256><<<NN, 256, 0, stream>>>(C, O, scale, shift, Ab, ldan);
  }

  hipMemsetAsync(pooled, 0, (size_t)GG*256*sizeof(float), stream);
  pool_kernel<<<dim3(GG, 8), 256, 0, stream>>>(Ab + 768, batch, pooled);
  final_kernel<<<GG, 128, 0, stream>>>(pooled, metaf, w1f, b1f, w2f, b2f_, d_out, flag);
}